// Round 8
// baseline (225.726 us; speedup 1.0000x reference)
//
#include <hip/hip_runtime.h>
#include <hip/hip_bf16.h>
#include <math.h>

#define BB 4
#define TT 4096
#define CC 1024
#define HH 64

typedef __attribute__((ext_vector_type(8))) short short8;          // MFMA A/B frag (8 bf16)
typedef __attribute__((ext_vector_type(8))) unsigned short ushort8;
typedef __attribute__((ext_vector_type(4))) float f32x4;           // MFMA C/D frag
typedef __attribute__((ext_vector_type(2))) unsigned int uint2v;   // 8B mover

// RNE float->bf16
__device__ inline unsigned short f2bf(float f) {
    unsigned int u = __builtin_bit_cast(unsigned int, f);
    unsigned int r = u + 0x7fffu + ((u >> 16) & 1u);
    return (unsigned short)(r >> 16);
}

// scratch-slot offset within a batch for 16-row strip qs >= 64
// (nc=2 for qs 64..127, 3 for 128..191, 4 for 192..255; 576 slots/batch)
__device__ inline int soff_strip(int qs) {
    if (qs < 128) return (qs - 64) * 2;
    if (qs < 192) return 128 + (qs - 128) * 3;
    return 320 + (qs - 192) * 4;
}

// ---------------------------------------------------------------------------
// Kernel 0: W -> frag-linear bf16 layout Wf.
// Wf[((kt*12 + ntl)*64 + lane)*8 + j] = W_{ntl>>2}[kt*32 + (lane>>4)*8 + j][(ntl&3)*16 + (lane&15)]
// ---------------------------------------------------------------------------
__global__ __launch_bounds__(256) void wtrans_kernel(
    const float* __restrict__ Wq,
    const float* __restrict__ Wk,
    const float* __restrict__ Wv,
    unsigned short* __restrict__ Wf)
{
    const int t = blockIdx.x * 256 + threadIdx.x;   // 0..24575
    const int lane = t & 63;
    const int ntl  = (t >> 6) % 12;
    const int kt   = t / 768;
    const int quad = lane >> 4, n = lane & 15;
    const int m    = ntl >> 2;
    const int col  = (ntl & 3) * 16 + n;
    const float* src = (m == 0) ? Wq : (m == 1) ? Wk : Wv;
    ushort8 u;
#pragma unroll
    for (int j = 0; j < 8; ++j)
        u[j] = f2bf(src[(kt * 32 + quad * 8 + j) * 64 + col]);
    *(ushort8*)(Wf + (size_t)t * 8) = u;
}

// ---------------------------------------------------------------------------
// Kernel 1: QKV GEMM [16384x1024]@[1024x192], split-K=2.
// 512 blocks x 256 thr = 4 waves: wave = (rg = wave&1, kh = wave>>1).
// Block = 32 rows; wave = 16 rows x 192 cols over k-half kh.
// Same-kh waves read the SAME Wf stream -> L1 sharing (Wf L2 traffic halved
// vs R7). LDS f32x4 reduce at end. Q pre-scaled by 1/32.
// ---------------------------------------------------------------------------
__global__ __launch_bounds__(256) void qkv_gemm(
    const float* __restrict__ x,
    const unsigned short* __restrict__ Wf,
    unsigned short* __restrict__ Qb,
    unsigned short* __restrict__ Kb,
    unsigned short* __restrict__ Vb)
{
    __shared__ f32x4 red[4][12][64];   // 48 KB

    const int tid  = threadIdx.x;
    const int lane = tid & 63;
    const int wave = tid >> 6;
    const int n    = lane & 15;
    const int quad = lane >> 4;
    const int rg   = wave & 1;         // row group
    const int kh   = wave >> 1;        // k half
    const int row0 = blockIdx.x * 32;

    // lane (quad,n) owns A[m=n][k=quad*8..+7] within each kt chunk of its half
    const float* xp = x + (size_t)(row0 + rg * 16 + n) * CC + kh * 512 + quad * 8;

    f32x4 acc[12];
#pragma unroll
    for (int i = 0; i < 12; ++i) acc[i] = (f32x4){0.f, 0.f, 0.f, 0.f};

    for (int kt = 0; kt < 16; ++kt) {
        const float4 f0 = *(const float4*)(xp + kt * 32);
        const float4 f1 = *(const float4*)(xp + kt * 32 + 4);
        short8 a;
        a[0] = (short)f2bf(f0.x); a[1] = (short)f2bf(f0.y);
        a[2] = (short)f2bf(f0.z); a[3] = (short)f2bf(f0.w);
        a[4] = (short)f2bf(f1.x); a[5] = (short)f2bf(f1.y);
        a[6] = (short)f2bf(f1.z); a[7] = (short)f2bf(f1.w);

        const int ktg = kh * 16 + kt;
        const unsigned short* wp = Wf + ((size_t)(ktg * 12) * 64 + lane) * 8;
#pragma unroll
        for (int ntl = 0; ntl < 12; ++ntl) {
            const short8 bw = *(const short8*)(wp + (size_t)ntl * 64 * 8);
            acc[ntl] = __builtin_amdgcn_mfma_f32_16x16x32_bf16(a, bw, acc[ntl], 0, 0, 0);
        }
    }

#pragma unroll
    for (int ntl = 0; ntl < 12; ++ntl) red[wave][ntl][lane] = acc[ntl];
    __syncthreads();

    // epilogue: wave w -> row group (w&1), ntl range (w>>1)*6..+5
    const int erg = wave & 1;
    const int nb  = (wave >> 1) * 6;
#pragma unroll
    for (int i = 0; i < 6; ++i) {
        const int ntl = nb + i;
        f32x4 s = red[erg][ntl][lane];       // kh = 0
        s += red[erg + 2][ntl][lane];        // kh = 1
        const int m    = ntl >> 2;
        const int colb = (ntl & 3) * 16;
        unsigned short* dst = (m == 0) ? Qb : (m == 1) ? Kb : Vb;
        const float sc = (m == 0) ? 0.03125f : 1.0f;
#pragma unroll
        for (int r = 0; r < 4; ++r) {
            const int row = row0 + erg * 16 + quad * 4 + r;
            dst[(size_t)row * HH + colb + n] = f2bf(s[r] * sc);
        }
    }
}

// ---------------------------------------------------------------------------
// Kernel 1b: V -> frag-linear V^T A-operand layout (K needs NO repack: the
// K A-frag pattern from row-major Kb already touches 16 fully-consumed 64B
// lines per load — same line count as a packed layout).
// Vf[r*8+j], r = (((b*64+st)*4+ht)*2+kk)*64+lane:
//   = Vb[b][st*64 + kk*32 + (lane>>4)*8 + j][ht*16 + (lane&15)]
// ---------------------------------------------------------------------------
__global__ __launch_bounds__(256) void v_repack(
    const unsigned short* __restrict__ Vb,
    unsigned short* __restrict__ Vf)
{
    const int r = blockIdx.x * 256 + threadIdx.x;   // 0..131071
    const int lane = r & 63;
    const int kk   = (r >> 6) & 1;
    const int tile = (r >> 7) & 3;
    const int st   = (r >> 9) & 63;
    const int b    = r >> 15;
    const int n = lane & 15, quad = lane >> 4;

    const int s0 = st * 64 + kk * 32 + quad * 8;
    const int h  = tile * 16 + n;
    ushort8 u;
#pragma unroll
    for (int j = 0; j < 8; ++j)
        u[j] = Vb[((size_t)b * TT + s0 + j) * HH + h];
    *(ushort8*)(Vf + (size_t)r * 8) = u;
}

// ---------------------------------------------------------------------------
// Kernel 2: flash attention — barrier-free, L1-shared K/V streams.
// Block = (b, q-group g of 4 strips, s-chunk ci); the 4 waves take
// qs = 4g..4g+3 with the SAME s-range (stmax = g for all), so their K/V
// loads hit L1 after the first wave. Whole block exits if ci >= nc.
// K A-frags DIRECT from Kb; V^T A-frags from Vf; only LDS = wave-private Ps.
// Fixed-max softmax -> linear partials -> split-s without max merge.
// ---------------------------------------------------------------------------
__global__ __launch_bounds__(256) void attn_kernel(
    const unsigned short* __restrict__ Qb,
    const unsigned short* __restrict__ Kb,
    const unsigned short* __restrict__ Vf,
    float* __restrict__ out,
    float* __restrict__ scr)
{
    const int b  = blockIdx.x >> 8;
    const int g  = (blockIdx.x >> 2) & 63;
    const int ci = blockIdx.x & 3;
    const int nc = (g + 16) >> 4;              // ceil((g+1)/16)
    if (ci >= nc) return;

    __shared__ unsigned short Ps[4][16][72];   // per-wave P strip [q][s]

    const int tid  = threadIdx.x;
    const int lane = tid & 63;
    const int wave = tid >> 6;
    const int n    = lane & 15;
    const int quad = lane >> 4;

    const int qs    = g * 4 + wave;            // this wave's 16-row strip
    const int stmax = g;
    const int st0   = ci << 4;
    const int stEnd = min(stmax, st0 + 15);
    const int qrow  = qs * 16 + n;

    // Q^T B-frags resident (Q pre-scaled by 1/32)
    const unsigned short* qp = Qb + ((size_t)b * TT + qrow) * HH;
    const short8 bQ0 = *(const short8*)(qp + quad * 8);
    const short8 bQ1 = *(const short8*)(qp + 32 + quad * 8);

    const unsigned short* KbB = Kb + (size_t)b * TT * HH;
    const unsigned short* VfB = Vf + (size_t)b * 262144;

    f32x4 O[4];
#pragma unroll
    for (int ht = 0; ht < 4; ++ht) O[ht] = (f32x4){0.f, 0.f, 0.f, 0.f};
    float l = 0.f;

    for (int st = st0; st <= stEnd; ++st) {
        // ---- S^T = K Q^T : K A-frags direct from row-major Kb ----
        f32x4 S[4];
#pragma unroll
        for (int mt = 0; mt < 4; ++mt) {
            const unsigned short* kp = KbB + (size_t)(st * 64 + mt * 16 + n) * HH + quad * 8;
            const short8 a0 = *(const short8*)(kp);
            const short8 a1 = *(const short8*)(kp + 32);
            f32x4 acc = (f32x4){0.f, 0.f, 0.f, 0.f};
            acc = __builtin_amdgcn_mfma_f32_16x16x32_bf16(a0, bQ0, acc, 0, 0, 0);
            acc = __builtin_amdgcn_mfma_f32_16x16x32_bf16(a1, bQ1, acc, 0, 0, 0);
            S[mt] = acc;
        }

        // ---- causal mask (diag tile): element row = s, col = qrow ----
        if (st == stmax) {
#pragma unroll
            for (int mt = 0; mt < 4; ++mt) {
                const int sg = st * 64 + mt * 16 + quad * 4;
#pragma unroll
                for (int r = 0; r < 4; ++r)
                    if (sg + r > qrow) S[mt][r] = -INFINITY;
            }
        }

        // ---- per-lane softmax accumulate (fixed max; exp(-inf)=0) ----
#pragma unroll
        for (int mt = 0; mt < 4; ++mt)
#pragma unroll
            for (int r = 0; r < 4; ++r) {
                const float p = __expf(fminf(S[mt][r], 30.f));
                S[mt][r] = p;
                l += p;
            }

        // ---- P -> wave-private LDS strip [q][s], read back as B-frags ----
#pragma unroll
        for (int mt = 0; mt < 4; ++mt) {
            uint2v w;
            w[0] = (unsigned int)f2bf(S[mt][0]) | ((unsigned int)f2bf(S[mt][1]) << 16);
            w[1] = (unsigned int)f2bf(S[mt][2]) | ((unsigned int)f2bf(S[mt][3]) << 16);
            *(uint2v*)&Ps[wave][n][mt * 16 + quad * 4] = w;
        }
        asm volatile("s_waitcnt lgkmcnt(0)" ::: "memory");   // wave-private; no barrier
        const short8 bP0 = *(const short8*)&Ps[wave][n][quad * 8];
        const short8 bP1 = *(const short8*)&Ps[wave][n][32 + quad * 8];

        // ---- O^T += V^T P^T : V^T A-frags from frag-linear Vf ----
#pragma unroll
        for (int ht = 0; ht < 4; ++ht) {
            const unsigned short* vp = VfB + (size_t)((st * 4 + ht) * 2) * 512 + lane * 8;
            const short8 a0 = *(const short8*)(vp);
            const short8 a1 = *(const short8*)(vp + 512);
            O[ht] = __builtin_amdgcn_mfma_f32_16x16x32_bf16(a0, bP0, O[ht], 0, 0, 0);
            O[ht] = __builtin_amdgcn_mfma_f32_16x16x32_bf16(a1, bP1, O[ht], 0, 0, 0);
        }
    }

    // ---- l: reduce across the 4 quads holding this q-row ----
    l += __shfl_xor(l, 16);
    l += __shfl_xor(l, 32);

    if (nc == 1) {
        const float inv = 1.0f / l;
        float* op = out + ((size_t)b * TT + qrow) * HH;
#pragma unroll
        for (int ht = 0; ht < 4; ++ht) {
            float4 o4;
            o4.x = O[ht][0] * inv;
            o4.y = O[ht][1] * inv;
            o4.z = O[ht][2] * inv;
            o4.w = O[ht][3] * inv;
            *(float4*)(op + ht * 16 + quad * 4) = o4;
        }
    } else {
        float* sb = scr + (size_t)(b * 576 + soff_strip(qs) + ci) * 1040;
        float* rp = sb + n * 64;
#pragma unroll
        for (int ht = 0; ht < 4; ++ht)
            *(f32x4*)(rp + ht * 16 + quad * 4) = O[ht];   // unnormalized
        if (quad == 0) sb[1024 + n] = l;
    }
}

// ---------------------------------------------------------------------------
// Kernel 3: combine partials for strips qs >= 64. 768 blocks x 64 thr.
// ---------------------------------------------------------------------------
__global__ __launch_bounds__(64) void combine_kernel(
    const float* __restrict__ scr,
    float* __restrict__ out)
{
    const int b  = blockIdx.x / 192;
    const int qs = 64 + blockIdx.x % 192;
    const int nc = ((qs >> 2) + 16) >> 4;
    const int base = b * 576 + soff_strip(qs);

    const int t    = threadIdx.x;
    const int row  = t >> 2;
    const int col0 = (t & 3) * 16;

    f32x4 s0 = (f32x4){0.f,0.f,0.f,0.f}, s1 = s0, s2 = s0, s3 = s0;
    float lsum = 0.f;
    for (int ci = 0; ci < nc; ++ci) {
        const float* sb = scr + (size_t)(base + ci) * 1040;
        lsum += sb[1024 + row];
        const float* p = sb + row * 64 + col0;
        s0 += *(const f32x4*)(p);
        s1 += *(const f32x4*)(p + 4);
        s2 += *(const f32x4*)(p + 8);
        s3 += *(const f32x4*)(p + 12);
    }
    const float inv = 1.0f / lsum;
    float* op = out + ((size_t)b * TT + qs * 16 + row) * HH + col0;
    *(f32x4*)(op)      = s0 * inv;
    *(f32x4*)(op + 4)  = s1 * inv;
    *(f32x4*)(op + 8)  = s2 * inv;
    *(f32x4*)(op + 12) = s3 * inv;
}

// ---------------------------------------------------------------------------
// ws layout (sequential, ~18 MB; harness ws is much larger):
//   [Qb 2MB][Kb 2MB][Vb 2MB][Wf 384KB][Vf 2MB][scr 9.585MB]
// ---------------------------------------------------------------------------
extern "C" void kernel_launch(void* const* d_in, const int* in_sizes, int n_in,
                              void* d_out, int out_size, void* d_ws, size_t ws_size,
                              hipStream_t stream)
{
    const float* x  = (const float*)d_in[0];
    const float* Wq = (const float*)d_in[1];
    const float* Wk = (const float*)d_in[2];
    const float* Wv = (const float*)d_in[3];

    unsigned short* Qb = (unsigned short*)d_ws;                    // 2 MB
    unsigned short* Kb = Qb + (size_t)BB * TT * HH;                // 2 MB
    unsigned short* Vb = Kb + (size_t)BB * TT * HH;                // 2 MB
    unsigned short* Wf = Vb + (size_t)BB * TT * HH;                // 384 KB
    unsigned short* Vf = Wf + (size_t)192 * 1024;                  // 2 MB
    float*          scr = (float*)(Vf + (size_t)BB * 262144);      // 9.585 MB
    float* out = (float*)d_out;

    wtrans_kernel<<<96, 256, 0, stream>>>(Wq, Wk, Wv, Wf);
    qkv_gemm<<<BB * TT / 32, 256, 0, stream>>>(x, Wf, Qb, Kb, Vb);
    v_repack<<<512, 256, 0, stream>>>(Vb, Vf);
    attn_kernel<<<BB * 64 * 4, 256, 0, stream>>>(Qb, Kb, Vf, out, scr);
    combine_kernel<<<768, 64, 0, stream>>>(scr, out);
}

// Round 9
// 159.988 us; speedup vs baseline: 1.4109x; 1.4109x over previous
//
#include <hip/hip_runtime.h>
#include <hip/hip_bf16.h>
#include <math.h>

#define BB 4
#define TT 4096
#define CC 1024
#define HH 64

typedef __attribute__((ext_vector_type(8))) short short8;          // MFMA A/B frag (8 bf16)
typedef __attribute__((ext_vector_type(8))) unsigned short ushort8;
typedef __attribute__((ext_vector_type(4))) float f32x4;           // MFMA C/D frag
typedef __attribute__((ext_vector_type(2))) unsigned int uint2v;   // 8B mover

// RNE float->bf16
__device__ inline unsigned short f2bf(float f) {
    unsigned int u = __builtin_bit_cast(unsigned int, f);
    unsigned int r = u + 0x7fffu + ((u >> 16) & 1u);
    return (unsigned short)(r >> 16);
}

// scratch-slot offset within a batch for 16-row strip qs >= 64
__device__ inline int soff_strip(int qs) {
    if (qs < 128) return (qs - 64) * 2;
    if (qs < 192) return 128 + (qs - 128) * 3;
    return 320 + (qs - 192) * 4;
}

// ---------------------------------------------------------------------------
// Kernel 0: W -> frag-linear bf16 layout Wf.
// ---------------------------------------------------------------------------
__global__ __launch_bounds__(256) void wtrans_kernel(
    const float* __restrict__ Wq,
    const float* __restrict__ Wk,
    const float* __restrict__ Wv,
    unsigned short* __restrict__ Wf)
{
    const int t = blockIdx.x * 256 + threadIdx.x;   // 0..24575
    const int lane = t & 63;
    const int ntl  = (t >> 6) % 12;
    const int kt   = t / 768;
    const int quad = lane >> 4, n = lane & 15;
    const int m    = ntl >> 2;
    const int col  = (ntl & 3) * 16 + n;
    const float* src = (m == 0) ? Wq : (m == 1) ? Wk : Wv;
    ushort8 u;
#pragma unroll
    for (int j = 0; j < 8; ++j)
        u[j] = f2bf(src[(kt * 32 + quad * 8 + j) * 64 + col]);
    *(ushort8*)(Wf + (size_t)t * 8) = u;
}

// ---------------------------------------------------------------------------
// Kernel 1: QKV GEMM, split-K over 4 waves (R7's proven loop) with a
// TWO-PHASE LDS reduce: 24 KB (vs R7's 48 KB) -> LDS blocks/CU cap 3->6.
// 1024 blocks x 256 thr; block = 16 rows; wave w covers k-quarter w.
// ---------------------------------------------------------------------------
__global__ __launch_bounds__(256) void qkv_gemm(
    const float* __restrict__ x,
    const unsigned short* __restrict__ Wf,
    unsigned short* __restrict__ Qb,
    unsigned short* __restrict__ Kb,
    unsigned short* __restrict__ Vb)
{
    __shared__ f32x4 red[2][12][64];   // 24 KB

    const int tid  = threadIdx.x;
    const int lane = tid & 63;
    const int wave = tid >> 6;
    const int n    = lane & 15;
    const int quad = lane >> 4;
    const int row0 = blockIdx.x * 16;

    const float* xp = x + (size_t)(row0 + n) * CC + wave * 256 + quad * 8;

    f32x4 acc[12];
#pragma unroll
    for (int i = 0; i < 12; ++i) acc[i] = (f32x4){0.f, 0.f, 0.f, 0.f};

#pragma unroll
    for (int kt = 0; kt < 8; ++kt) {
        const float4 f0 = *(const float4*)(xp + kt * 32);
        const float4 f1 = *(const float4*)(xp + kt * 32 + 4);
        short8 a;
        a[0] = (short)f2bf(f0.x); a[1] = (short)f2bf(f0.y);
        a[2] = (short)f2bf(f0.z); a[3] = (short)f2bf(f0.w);
        a[4] = (short)f2bf(f1.x); a[5] = (short)f2bf(f1.y);
        a[6] = (short)f2bf(f1.z); a[7] = (short)f2bf(f1.w);

        const unsigned short* wp = Wf + ((size_t)((wave * 8 + kt) * 12) * 64 + lane) * 8;
#pragma unroll
        for (int ntl = 0; ntl < 12; ++ntl) {
            const short8 bw = *(const short8*)(wp + (size_t)ntl * 64 * 8);
            acc[ntl] = __builtin_amdgcn_mfma_f32_16x16x32_bf16(a, bw, acc[ntl], 0, 0, 0);
        }
    }

    // phase 1: waves 2,3 dump; waves 0,1 add
    if (wave >= 2) {
#pragma unroll
        for (int ntl = 0; ntl < 12; ++ntl) red[wave - 2][ntl][lane] = acc[ntl];
    }
    __syncthreads();
    if (wave < 2) {
#pragma unroll
        for (int ntl = 0; ntl < 12; ++ntl) acc[ntl] += red[wave][ntl][lane];
    }
    __syncthreads();
    // phase 2: wave 1 dumps; wave 0 finalizes + epilogue
    if (wave == 1) {
#pragma unroll
        for (int ntl = 0; ntl < 12; ++ntl) red[0][ntl][lane] = acc[ntl];
    }
    __syncthreads();
    if (wave == 0) {
#pragma unroll
        for (int ntl = 0; ntl < 12; ++ntl) {
            f32x4 s = acc[ntl] + red[0][ntl][lane];
            const int m    = ntl >> 2;
            const int colb = (ntl & 3) * 16;
            unsigned short* dst = (m == 0) ? Qb : (m == 1) ? Kb : Vb;
            const float sc = (m == 0) ? 0.03125f : 1.0f;
#pragma unroll
            for (int r = 0; r < 4; ++r) {
                const int row = row0 + quad * 4 + r;
                dst[(size_t)row * HH + colb + n] = f2bf(s[r] * sc);
            }
        }
    }
}

// ---------------------------------------------------------------------------
// Kernel 1b: K/V -> frag-linear A-operand layouts (R7 verbatim — proven).
// Kf[r*8+j], r = (((b*64+st)*4+mt)*2+kk)*64+lane
//   = Kb[b][st*64 + mt*16 + (lane&15)][kk*32 + (lane>>4)*8 + j]
// Vf same nesting (tile=ht): Vb[b][st*64+kk*32+(lane>>4)*8+j][ht*16+(lane&15)]
// ---------------------------------------------------------------------------
__global__ __launch_bounds__(256) void kv_repack(
    const unsigned short* __restrict__ Kb,
    const unsigned short* __restrict__ Vb,
    unsigned short* __restrict__ Kf,
    unsigned short* __restrict__ Vf)
{
    const int t = blockIdx.x * 256 + threadIdx.x;   // 0..262143
    const int mat  = t >> 17;
    const int r    = t & 131071;
    const int lane = r & 63;
    const int kk   = (r >> 6) & 1;
    const int tile = (r >> 7) & 3;
    const int st   = (r >> 9) & 63;
    const int b    = r >> 15;
    const int n = lane & 15, quad = lane >> 4;

    if (mat == 0) {
        const unsigned short* src =
            Kb + ((size_t)b * TT + st * 64 + tile * 16 + n) * HH + kk * 32 + quad * 8;
        *(ushort8*)(Kf + (size_t)r * 8) = *(const ushort8*)src;
    } else {
        const int s0 = st * 64 + kk * 32 + quad * 8;
        const int h  = tile * 16 + n;
        ushort8 u;
#pragma unroll
        for (int j = 0; j < 8; ++j)
            u[j] = Vb[((size_t)b * TT + s0 + j) * HH + h];
        *(ushort8*)(Vf + (size_t)r * 8) = u;
    }
}

// ---------------------------------------------------------------------------
// Kernel 2: flash attention — R7 structure (frag-linear Kf/Vf, barrier-free,
// wave-independent units) + COMPACT grid: wid -> (b, qs, ci) via closed-form
// prefix-sum inverse, so all 2560 launched waves are active (vs R7's 2560
// of 4096). Fixed-max softmax -> linear partials -> split-s, no max merge.
// ---------------------------------------------------------------------------
__global__ __launch_bounds__(256) void attn_kernel(
    const unsigned short* __restrict__ Qb,
    const unsigned short* __restrict__ Kf,
    const unsigned short* __restrict__ Vf,
    float* __restrict__ out,
    float* __restrict__ scr)
{
    __shared__ unsigned short Ps[4][16][72];   // per-wave P strip [q][s]

    const int tid  = threadIdx.x;
    const int lane = tid & 63;
    const int wave = tid >> 6;
    const int n    = lane & 15;
    const int quad = lane >> 4;

    const int wid = blockIdx.x * 4 + wave;     // 0..2559
    const int b   = wid / 640;
    const int u   = wid - b * 640;

    // prefix-sum inverse: u -> (qs, ci), nc(qs) = (qs>>2 + 16)>>4
    int qs, ci;
    if (u < 64)        { qs = u;                  ci = 0; }
    else if (u < 192)  { const int v = u - 64;  qs = 64  + (v >> 1); ci = v & 1; }
    else if (u < 384)  { const int v = u - 192; const int d = v / 3;
                         qs = 128 + d;            ci = v - 3 * d; }
    else               { const int v = u - 384; qs = 192 + (v >> 2); ci = v & 3; }

    const int stmax = qs >> 2;
    const int st0   = ci << 4;
    const int stEnd = min(stmax, st0 + 15);
    const int nc    = (stmax + 16) >> 4;
    const int qrow  = qs * 16 + n;

    // Q^T B-frags resident (Q pre-scaled by 1/32)
    const unsigned short* qp = Qb + ((size_t)b * TT + qrow) * HH;
    const short8 bQ0 = *(const short8*)(qp + quad * 8);
    const short8 bQ1 = *(const short8*)(qp + 32 + quad * 8);

    const unsigned short* KfB = Kf + (size_t)b * 262144;
    const unsigned short* VfB = Vf + (size_t)b * 262144;

    f32x4 O[4];
#pragma unroll
    for (int ht = 0; ht < 4; ++ht) O[ht] = (f32x4){0.f, 0.f, 0.f, 0.f};
    float l = 0.f;

    for (int st = st0; st <= stEnd; ++st) {
        // ---- S^T = K Q^T : K A-frags = coalesced dwordx4 from Kf ----
        f32x4 S[4];
#pragma unroll
        for (int mt = 0; mt < 4; ++mt) {
            const unsigned short* kp = KfB + (size_t)((st * 4 + mt) * 2) * 512 + lane * 8;
            const short8 a0 = *(const short8*)(kp);
            const short8 a1 = *(const short8*)(kp + 512);
            f32x4 acc = (f32x4){0.f, 0.f, 0.f, 0.f};
            acc = __builtin_amdgcn_mfma_f32_16x16x32_bf16(a0, bQ0, acc, 0, 0, 0);
            acc = __builtin_amdgcn_mfma_f32_16x16x32_bf16(a1, bQ1, acc, 0, 0, 0);
            S[mt] = acc;
        }

        // ---- causal mask (diag tile): element row = s, col = qrow ----
        if (st == stmax) {
#pragma unroll
            for (int mt = 0; mt < 4; ++mt) {
                const int sg = st * 64 + mt * 16 + quad * 4;
#pragma unroll
                for (int r = 0; r < 4; ++r)
                    if (sg + r > qrow) S[mt][r] = -INFINITY;
            }
        }

        // ---- per-lane softmax accumulate (fixed max; exp(-inf)=0) ----
#pragma unroll
        for (int mt = 0; mt < 4; ++mt)
#pragma unroll
            for (int r = 0; r < 4; ++r) {
                const float p = __expf(fminf(S[mt][r], 30.f));
                S[mt][r] = p;
                l += p;
            }

        // ---- P -> wave-private LDS strip [q][s], read back as B-frags ----
#pragma unroll
        for (int mt = 0; mt < 4; ++mt) {
            uint2v w;
            w[0] = (unsigned int)f2bf(S[mt][0]) | ((unsigned int)f2bf(S[mt][1]) << 16);
            w[1] = (unsigned int)f2bf(S[mt][2]) | ((unsigned int)f2bf(S[mt][3]) << 16);
            *(uint2v*)&Ps[wave][n][mt * 16 + quad * 4] = w;
        }
        asm volatile("s_waitcnt lgkmcnt(0)" ::: "memory");   // wave-private; no barrier
        const short8 bP0 = *(const short8*)&Ps[wave][n][quad * 8];
        const short8 bP1 = *(const short8*)&Ps[wave][n][32 + quad * 8];

        // ---- O^T += V^T P^T : V^T A-frags = coalesced dwordx4 from Vf ----
#pragma unroll
        for (int ht = 0; ht < 4; ++ht) {
            const unsigned short* vp = VfB + (size_t)((st * 4 + ht) * 2) * 512 + lane * 8;
            const short8 a0 = *(const short8*)(vp);
            const short8 a1 = *(const short8*)(vp + 512);
            O[ht] = __builtin_amdgcn_mfma_f32_16x16x32_bf16(a0, bP0, O[ht], 0, 0, 0);
            O[ht] = __builtin_amdgcn_mfma_f32_16x16x32_bf16(a1, bP1, O[ht], 0, 0, 0);
        }
    }

    // ---- l: reduce across the 4 quads holding this q-row ----
    l += __shfl_xor(l, 16);
    l += __shfl_xor(l, 32);

    if (nc == 1) {
        const float inv = 1.0f / l;
        float* op = out + ((size_t)b * TT + qrow) * HH;
#pragma unroll
        for (int ht = 0; ht < 4; ++ht) {
            float4 o4;
            o4.x = O[ht][0] * inv;
            o4.y = O[ht][1] * inv;
            o4.z = O[ht][2] * inv;
            o4.w = O[ht][3] * inv;
            *(float4*)(op + ht * 16 + quad * 4) = o4;
        }
    } else {
        float* sb = scr + (size_t)(b * 576 + soff_strip(qs) + ci) * 1040;
        float* rp = sb + n * 64;
#pragma unroll
        for (int ht = 0; ht < 4; ++ht)
            *(f32x4*)(rp + ht * 16 + quad * 4) = O[ht];   // unnormalized
        if (quad == 0) sb[1024 + n] = l;
    }
}

// ---------------------------------------------------------------------------
// Kernel 3: combine partials for strips qs >= 64. 768 blocks x 64 thr.
// ---------------------------------------------------------------------------
__global__ __launch_bounds__(64) void combine_kernel(
    const float* __restrict__ scr,
    float* __restrict__ out)
{
    const int b  = blockIdx.x / 192;
    const int qs = 64 + blockIdx.x % 192;
    const int nc = ((qs >> 2) + 16) >> 4;
    const int base = b * 576 + soff_strip(qs);

    const int t    = threadIdx.x;
    const int row  = t >> 2;
    const int col0 = (t & 3) * 16;

    f32x4 s0 = (f32x4){0.f,0.f,0.f,0.f}, s1 = s0, s2 = s0, s3 = s0;
    float lsum = 0.f;
    for (int ci = 0; ci < nc; ++ci) {
        const float* sb = scr + (size_t)(base + ci) * 1040;
        lsum += sb[1024 + row];
        const float* p = sb + row * 64 + col0;
        s0 += *(const f32x4*)(p);
        s1 += *(const f32x4*)(p + 4);
        s2 += *(const f32x4*)(p + 8);
        s3 += *(const f32x4*)(p + 12);
    }
    const float inv = 1.0f / lsum;
    float* op = out + ((size_t)b * TT + qs * 16 + row) * HH + col0;
    *(f32x4*)(op)      = s0 * inv;
    *(f32x4*)(op + 4)  = s1 * inv;
    *(f32x4*)(op + 8)  = s2 * inv;
    *(f32x4*)(op + 12) = s3 * inv;
}

// ---------------------------------------------------------------------------
// ws layout (sequential, ~20 MB):
//   [Qb 2MB][Kb 2MB][Vb 2MB][Wf 384KB][Kf 2MB][Vf 2MB][scr 9.585MB]
// ---------------------------------------------------------------------------
extern "C" void kernel_launch(void* const* d_in, const int* in_sizes, int n_in,
                              void* d_out, int out_size, void* d_ws, size_t ws_size,
                              hipStream_t stream)
{
    const float* x  = (const float*)d_in[0];
    const float* Wq = (const float*)d_in[1];
    const float* Wk = (const float*)d_in[2];
    const float* Wv = (const float*)d_in[3];

    unsigned short* Qb = (unsigned short*)d_ws;                    // 2 MB
    unsigned short* Kb = Qb + (size_t)BB * TT * HH;                // 2 MB
    unsigned short* Vb = Kb + (size_t)BB * TT * HH;                // 2 MB
    unsigned short* Wf = Vb + (size_t)BB * TT * HH;                // 384 KB
    unsigned short* Kf = Wf + (size_t)192 * 1024;                  // 2 MB
    unsigned short* Vf = Kf + (size_t)BB * 262144;                 // 2 MB
    float*          scr = (float*)(Vf + (size_t)BB * 262144);      // 9.585 MB
    float* out = (float*)d_out;

    wtrans_kernel<<<96, 256, 0, stream>>>(Wq, Wk, Wv, Wf);
    qkv_gemm<<<BB * TT / 16, 256, 0, stream>>>(x, Wf, Qb, Kb, Vb);
    kv_repack<<<1024, 256, 0, stream>>>(Kb, Vb, Kf, Vf);
    attn_kernel<<<640, 256, 0, stream>>>(Qb, Kf, Vf, out, scr);
    combine_kernel<<<768, 64, 0, stream>>>(scr, out);
}

// Round 11
// 158.402 us; speedup vs baseline: 1.4250x; 1.0100x over previous
//
#include <hip/hip_runtime.h>
#include <hip/hip_bf16.h>
#include <math.h>

#define BB 4
#define TT 4096
#define CC 1024
#define HH 64

typedef __attribute__((ext_vector_type(8))) short short8;          // MFMA A/B frag (8 bf16)
typedef __attribute__((ext_vector_type(8))) unsigned short ushort8;
typedef __attribute__((ext_vector_type(4))) float f32x4;           // MFMA C/D frag
typedef __attribute__((ext_vector_type(2))) unsigned int uint2v;   // 8B mover

// RNE float->bf16
__device__ inline unsigned short f2bf(float f) {
    unsigned int u = __builtin_bit_cast(unsigned int, f);
    unsigned int r = u + 0x7fffu + ((u >> 16) & 1u);
    return (unsigned short)(r >> 16);
}

// scratch-slot offset within a batch for 16-row strip qs >= 64
__device__ inline int soff_strip(int qs) {
    if (qs < 128) return (qs - 64) * 2;
    if (qs < 192) return 128 + (qs - 128) * 3;
    return 320 + (qs - 192) * 4;
}

// ---------------------------------------------------------------------------
// Kernel 0: W -> frag-linear bf16 layout Wf (unchanged, proven).
// ---------------------------------------------------------------------------
__global__ __launch_bounds__(256) void wtrans_kernel(
    const float* __restrict__ Wq,
    const float* __restrict__ Wk,
    const float* __restrict__ Wv,
    unsigned short* __restrict__ Wf)
{
    const int t = blockIdx.x * 256 + threadIdx.x;   // 0..24575
    const int lane = t & 63;
    const int ntl  = (t >> 6) % 12;
    const int kt   = t / 768;
    const int quad = lane >> 4, n = lane & 15;
    const int m    = ntl >> 2;
    const int col  = (ntl & 3) * 16 + n;
    const float* src = (m == 0) ? Wq : (m == 1) ? Wk : Wv;
    ushort8 u;
#pragma unroll
    for (int j = 0; j < 8; ++j)
        u[j] = f2bf(src[(kt * 32 + quad * 8 + j) * 64 + col]);
    *(ushort8*)(Wf + (size_t)t * 8) = u;
}

// ---------------------------------------------------------------------------
// Kernel 1: QKV GEMM [16384x1024]@[1024x192], split-K over 4 waves.
// 512 blocks x 256 thr; block = 32 rows (2 m-tiles); wave = k-quarter.
// After the LDS k-reduce the block deposits its 32x192 fp32 tile into Tl
// and writes Qb (row-major, pre-scaled 1/32) and Kf/Vf (frag-linear)
// directly — no kv_repack round-trip.
// FIX vs R10: Tl now overlays ONLY red[1] (dead after the phase-1 add);
// R10 overlaid red[0] and wave-0's Tl writes clobbered its own pending
// red[0] reads (intra-wave read/write race across loop iterations).
// ---------------------------------------------------------------------------
__global__ __launch_bounds__(256) void qkv_gemm(
    const float* __restrict__ x,
    const unsigned short* __restrict__ Wf,
    unsigned short* __restrict__ Qb,
    unsigned short* __restrict__ Kf,
    unsigned short* __restrict__ Vf)
{
    __shared__ __align__(16) unsigned char smem[50176];   // 49 KB
    f32x4 (*red)[24][64] = (f32x4 (*)[24][64])smem;       // red[2][24][64] (48 KB)
    float (*Tl)[200]     = (float (*)[200])(smem + 24576); // Tl[32][200] over red[1] ONLY

    const int tid  = threadIdx.x;
    const int lane = tid & 63;
    const int wave = tid >> 6;          // = k-quarter
    const int n    = lane & 15;
    const int quad = lane >> 4;

    const int row0g = blockIdx.x * 32;            // global row
    const int b     = row0g >> 12;
    const int trow  = row0g & (TT - 1);
    const int st    = trow >> 6;
    const int mtb   = (trow >> 4) & 3;            // 0 or 2
    const int kkv   = (trow >> 5) & 1;

    // lane (quad,n) owns rows n and n+16; k = wave*256 + kt*32 + quad*8 + j
    const float* xp0 = x + (size_t)(row0g + n) * CC + wave * 256 + quad * 8;
    const float* xp1 = xp0 + 16 * CC;

    f32x4 acc[2][12];
#pragma unroll
    for (int mtl = 0; mtl < 2; ++mtl)
#pragma unroll
        for (int i = 0; i < 12; ++i) acc[mtl][i] = (f32x4){0.f, 0.f, 0.f, 0.f};

#pragma unroll
    for (int kt = 0; kt < 8; ++kt) {
        const float4 f0 = *(const float4*)(xp0 + kt * 32);
        const float4 f1 = *(const float4*)(xp0 + kt * 32 + 4);
        const float4 g0 = *(const float4*)(xp1 + kt * 32);
        const float4 g1 = *(const float4*)(xp1 + kt * 32 + 4);
        short8 a0, a1;
        a0[0] = (short)f2bf(f0.x); a0[1] = (short)f2bf(f0.y);
        a0[2] = (short)f2bf(f0.z); a0[3] = (short)f2bf(f0.w);
        a0[4] = (short)f2bf(f1.x); a0[5] = (short)f2bf(f1.y);
        a0[6] = (short)f2bf(f1.z); a0[7] = (short)f2bf(f1.w);
        a1[0] = (short)f2bf(g0.x); a1[1] = (short)f2bf(g0.y);
        a1[2] = (short)f2bf(g0.z); a1[3] = (short)f2bf(g0.w);
        a1[4] = (short)f2bf(g1.x); a1[5] = (short)f2bf(g1.y);
        a1[6] = (short)f2bf(g1.z); a1[7] = (short)f2bf(g1.w);

        const unsigned short* wp = Wf + ((size_t)((wave * 8 + kt) * 12) * 64 + lane) * 8;
#pragma unroll
        for (int ntl = 0; ntl < 12; ++ntl) {
            const short8 bw = *(const short8*)(wp + (size_t)ntl * 64 * 8);
            acc[0][ntl] = __builtin_amdgcn_mfma_f32_16x16x32_bf16(a0, bw, acc[0][ntl], 0, 0, 0);
            acc[1][ntl] = __builtin_amdgcn_mfma_f32_16x16x32_bf16(a1, bw, acc[1][ntl], 0, 0, 0);
        }
    }

    // ---- k-reduce across the 4 waves (order = (w0+w2)+(w1+w3), as R9) ----
    if (wave >= 2) {
#pragma unroll
        for (int mtl = 0; mtl < 2; ++mtl)
#pragma unroll
            for (int ntl = 0; ntl < 12; ++ntl)
                red[wave - 2][mtl * 12 + ntl][lane] = acc[mtl][ntl];
    }
    __syncthreads();
    if (wave < 2) {
#pragma unroll
        for (int mtl = 0; mtl < 2; ++mtl)
#pragma unroll
            for (int ntl = 0; ntl < 12; ++ntl)
                acc[mtl][ntl] += red[wave][mtl * 12 + ntl][lane];
    }
    __syncthreads();   // red[1] dead beyond this point
    if (wave == 1) {
#pragma unroll
        for (int mtl = 0; mtl < 2; ++mtl)
#pragma unroll
            for (int ntl = 0; ntl < 12; ++ntl)
                red[0][mtl * 12 + ntl][lane] = acc[mtl][ntl];
    }
    __syncthreads();
    if (wave == 0) {
        // finalize and deposit the 32x192 fp32 tile into Tl (disjoint from red[0])
#pragma unroll
        for (int mtl = 0; mtl < 2; ++mtl)
#pragma unroll
            for (int ntl = 0; ntl < 12; ++ntl) {
                const f32x4 s = acc[mtl][ntl] + red[0][mtl * 12 + ntl][lane];
                const int col = (ntl >> 2) * 64 + (ntl & 3) * 16 + n;
#pragma unroll
                for (int r = 0; r < 4; ++r)
                    Tl[mtl * 16 + quad * 4 + r][col] = s[r];
            }
    }
    __syncthreads();

    // ---- epilogue from Tl (all 256 threads) ----
    // Q: row-major bf16, pre-scaled by C^-0.5 = 1/32
    {
        const int row = tid & 31;
        const int cq  = (tid >> 5) * 8;
        ushort8 u;
#pragma unroll
        for (int j = 0; j < 8; ++j)
            u[j] = f2bf(Tl[row][cq + j] * 0.03125f);
        *(ushort8*)(Qb + (size_t)(row0g + row) * HH + cq) = u;
    }
    // K frag-linear: wave g = (mtl = g&1, kk = g>>1)
    {
        const int mtl = wave & 1;
        const int kk  = wave >> 1;
        ushort8 u;
#pragma unroll
        for (int j = 0; j < 8; ++j)
            u[j] = f2bf(Tl[mtl * 16 + n][64 + kk * 32 + quad * 8 + j]);
        const size_t r = (size_t)(((b * 64 + st) * 4 + (mtb + mtl)) * 2 + kk) * 64 + lane;
        *(ushort8*)(Kf + r * 8) = u;
    }
    // V frag-linear (V^T frags): wave g = ht; kk fixed by the 32-row half
    {
        const int ht = wave;
        ushort8 u;
#pragma unroll
        for (int j = 0; j < 8; ++j)
            u[j] = f2bf(Tl[quad * 8 + j][128 + ht * 16 + n]);
        const size_t r = (size_t)(((b * 64 + st) * 4 + ht) * 2 + kkv) * 64 + lane;
        *(ushort8*)(Vf + r * 8) = u;
    }
}

// ---------------------------------------------------------------------------
// Kernel 2: flash attention — R9 compact structure + cross-iteration overlap:
// double-buffered Ps and register K-frag prefetch / early V-frag loads.
// ---------------------------------------------------------------------------
__global__ __launch_bounds__(256) void attn_kernel(
    const unsigned short* __restrict__ Qb,
    const unsigned short* __restrict__ Kf,
    const unsigned short* __restrict__ Vf,
    float* __restrict__ out,
    float* __restrict__ scr)
{
    __shared__ unsigned short Ps[4][2][16][72];   // per-wave double-buffered P strip

    const int tid  = threadIdx.x;
    const int lane = tid & 63;
    const int wave = tid >> 6;
    const int n    = lane & 15;
    const int quad = lane >> 4;

    const int wid = blockIdx.x * 4 + wave;     // 0..2559
    const int b   = wid / 640;
    const int u   = wid - b * 640;

    // prefix-sum inverse: u -> (qs, ci), nc(qs) = (qs>>2 + 16)>>4
    int qs, ci;
    if (u < 64)        { qs = u;                  ci = 0; }
    else if (u < 192)  { const int v = u - 64;  qs = 64  + (v >> 1); ci = v & 1; }
    else if (u < 384)  { const int v = u - 192; const int d = v / 3;
                         qs = 128 + d;            ci = v - 3 * d; }
    else               { const int v = u - 384; qs = 192 + (v >> 2); ci = v & 3; }

    const int stmax = qs >> 2;
    const int st0   = ci << 4;
    const int stEnd = min(stmax, st0 + 15);
    const int nc    = (stmax + 16) >> 4;
    const int qrow  = qs * 16 + n;

    // Q^T B-frags resident (Q pre-scaled by 1/32)
    const unsigned short* qp = Qb + ((size_t)b * TT + qrow) * HH;
    const short8 bQ0 = *(const short8*)(qp + quad * 8);
    const short8 bQ1 = *(const short8*)(qp + 32 + quad * 8);

    const unsigned short* KfB = Kf + (size_t)b * 262144;
    const unsigned short* VfB = Vf + (size_t)b * 262144;

    f32x4 O[4];
#pragma unroll
    for (int ht = 0; ht < 4; ++ht) O[ht] = (f32x4){0.f, 0.f, 0.f, 0.f};
    float l = 0.f;

    // preload K frags for st0
    short8 kA[4], kB[4];
#pragma unroll
    for (int mt = 0; mt < 4; ++mt) {
        const unsigned short* kp = KfB + (size_t)((st0 * 4 + mt) * 2) * 512 + lane * 8;
        kA[mt] = *(const short8*)(kp);
        kB[mt] = *(const short8*)(kp + 512);
    }

    for (int st = st0; st <= stEnd; ++st) {
        // ---- S^T = K Q^T from resident K frags ----
        f32x4 S[4];
#pragma unroll
        for (int mt = 0; mt < 4; ++mt) {
            f32x4 acc = (f32x4){0.f, 0.f, 0.f, 0.f};
            acc = __builtin_amdgcn_mfma_f32_16x16x32_bf16(kA[mt], bQ0, acc, 0, 0, 0);
            acc = __builtin_amdgcn_mfma_f32_16x16x32_bf16(kB[mt], bQ1, acc, 0, 0, 0);
            S[mt] = acc;
        }

        // ---- V frags for THIS st (latency overlaps exp/LDS below) ----
        short8 vA[4], vB[4];
#pragma unroll
        for (int ht = 0; ht < 4; ++ht) {
            const unsigned short* vp = VfB + (size_t)((st * 4 + ht) * 2) * 512 + lane * 8;
            vA[ht] = *(const short8*)(vp);
            vB[ht] = *(const short8*)(vp + 512);
        }
        // ---- K prefetch for st+1 ----
        if (st < stEnd) {
#pragma unroll
            for (int mt = 0; mt < 4; ++mt) {
                const unsigned short* kp = KfB + (size_t)(((st + 1) * 4 + mt) * 2) * 512 + lane * 8;
                kA[mt] = *(const short8*)(kp);
                kB[mt] = *(const short8*)(kp + 512);
            }
        }

        // ---- causal mask (diag tile): element row = s, col = qrow ----
        if (st == stmax) {
#pragma unroll
            for (int mt = 0; mt < 4; ++mt) {
                const int sg = st * 64 + mt * 16 + quad * 4;
#pragma unroll
                for (int r = 0; r < 4; ++r)
                    if (sg + r > qrow) S[mt][r] = -INFINITY;
            }
        }

        // ---- per-lane softmax accumulate (fixed max; exp(-inf)=0) ----
#pragma unroll
        for (int mt = 0; mt < 4; ++mt)
#pragma unroll
            for (int r = 0; r < 4; ++r) {
                const float p = __expf(fminf(S[mt][r], 30.f));
                S[mt][r] = p;
                l += p;
            }

        // ---- P -> wave-private double-buffered LDS strip, read as B-frags ----
        const int pp = st & 1;
#pragma unroll
        for (int mt = 0; mt < 4; ++mt) {
            uint2v w;
            w[0] = (unsigned int)f2bf(S[mt][0]) | ((unsigned int)f2bf(S[mt][1]) << 16);
            w[1] = (unsigned int)f2bf(S[mt][2]) | ((unsigned int)f2bf(S[mt][3]) << 16);
            *(uint2v*)&Ps[wave][pp][n][mt * 16 + quad * 4] = w;
        }
        asm volatile("s_waitcnt lgkmcnt(0)" ::: "memory");   // wave-private; no barrier
        const short8 bP0 = *(const short8*)&Ps[wave][pp][n][quad * 8];
        const short8 bP1 = *(const short8*)&Ps[wave][pp][n][32 + quad * 8];

        // ---- O^T += V^T P^T from resident V frags ----
#pragma unroll
        for (int ht = 0; ht < 4; ++ht) {
            O[ht] = __builtin_amdgcn_mfma_f32_16x16x32_bf16(vA[ht], bP0, O[ht], 0, 0, 0);
            O[ht] = __builtin_amdgcn_mfma_f32_16x16x32_bf16(vB[ht], bP1, O[ht], 0, 0, 0);
        }
    }

    // ---- l: reduce across the 4 quads holding this q-row ----
    l += __shfl_xor(l, 16);
    l += __shfl_xor(l, 32);

    if (nc == 1) {
        const float inv = 1.0f / l;
        float* op = out + ((size_t)b * TT + qrow) * HH;
#pragma unroll
        for (int ht = 0; ht < 4; ++ht) {
            float4 o4;
            o4.x = O[ht][0] * inv;
            o4.y = O[ht][1] * inv;
            o4.z = O[ht][2] * inv;
            o4.w = O[ht][3] * inv;
            *(float4*)(op + ht * 16 + quad * 4) = o4;
        }
    } else {
        float* sb = scr + (size_t)(b * 576 + soff_strip(qs) + ci) * 1040;
        float* rp = sb + n * 64;
#pragma unroll
        for (int ht = 0; ht < 4; ++ht)
            *(f32x4*)(rp + ht * 16 + quad * 4) = O[ht];   // unnormalized
        if (quad == 0) sb[1024 + n] = l;
    }
}

// ---------------------------------------------------------------------------
// Kernel 3: combine partials for strips qs >= 64. 768 blocks x 64 thr.
// ---------------------------------------------------------------------------
__global__ __launch_bounds__(64) void combine_kernel(
    const float* __restrict__ scr,
    float* __restrict__ out)
{
    const int b  = blockIdx.x / 192;
    const int qs = 64 + blockIdx.x % 192;
    const int nc = ((qs >> 2) + 16) >> 4;
    const int base = b * 576 + soff_strip(qs);

    const int t    = threadIdx.x;
    const int row  = t >> 2;
    const int col0 = (t & 3) * 16;

    f32x4 s0 = (f32x4){0.f,0.f,0.f,0.f}, s1 = s0, s2 = s0, s3 = s0;
    float lsum = 0.f;
    for (int ci = 0; ci < nc; ++ci) {
        const float* sb = scr + (size_t)(base + ci) * 1040;
        lsum += sb[1024 + row];
        const float* p = sb + row * 64 + col0;
        s0 += *(const f32x4*)(p);
        s1 += *(const f32x4*)(p + 4);
        s2 += *(const f32x4*)(p + 8);
        s3 += *(const f32x4*)(p + 12);
    }
    const float inv = 1.0f / lsum;
    float* op = out + ((size_t)b * TT + qs * 16 + row) * HH + col0;
    *(f32x4*)(op)      = s0 * inv;
    *(f32x4*)(op + 4)  = s1 * inv;
    *(f32x4*)(op + 8)  = s2 * inv;
    *(f32x4*)(op + 12) = s3 * inv;
}

// ---------------------------------------------------------------------------
// ws layout (~16 MB): [Qb 2MB][Wf 384KB][Kf 2MB][Vf 2MB][scr 9.585MB]
// ---------------------------------------------------------------------------
extern "C" void kernel_launch(void* const* d_in, const int* in_sizes, int n_in,
                              void* d_out, int out_size, void* d_ws, size_t ws_size,
                              hipStream_t stream)
{
    const float* x  = (const float*)d_in[0];
    const float* Wq = (const float*)d_in[1];
    const float* Wk = (const float*)d_in[2];
    const float* Wv = (const float*)d_in[3];

    unsigned short* Qb = (unsigned short*)d_ws;                    // 2 MB
    unsigned short* Wf = Qb + (size_t)BB * TT * HH;                // 384 KB
    unsigned short* Kf = Wf + (size_t)192 * 1024;                  // 2 MB
    unsigned short* Vf = Kf + (size_t)BB * 262144;                 // 2 MB
    float*          scr = (float*)(Vf + (size_t)BB * 262144);      // 9.585 MB
    float* out = (float*)d_out;

    wtrans_kernel<<<96, 256, 0, stream>>>(Wq, Wk, Wv, Wf);
    qkv_gemm<<<BB * TT / 32, 256, 0, stream>>>(x, Wf, Qb, Kf, Vf);
    attn_kernel<<<640, 256, 0, stream>>>(Qb, Kf, Vf, out, scr);
    combine_kernel<<<768, 64, 0, stream>>>(scr, out);
}